// Round 12
// baseline (1018.417 us; speedup 1.0000x reference)
//
#include <hip/hip_runtime.h>

#define NODES   131072
#define EDGES   2097152
#define H       128
#define NB      32        // graphs
#define PP      4096      // nodes per problem graph

typedef short bf16x8 __attribute__((ext_vector_type(8)));
typedef float f32x4  __attribute__((ext_vector_type(4)));
typedef float f32x2  __attribute__((ext_vector_type(2)));
typedef unsigned short u16;

// packed-weight element offsets
#define RZE 65536
#define AIE 16384
#define AHE 16384
#define LYRE (RZE + AIE + AHE)   // 98304 per conv layer

// ============================================================================
// INIT (1 launch): block 0 inits pcur + ticket + zeroes ge; blocks 1..32
// compute item-value dot (out[b] = iv . sol[0]) — depends only on inputs,
// plain store precedes l1l2's bound atomics in stream order.
// ============================================================================
#define CAPP 18432

__global__ __launch_bounds__(256) void gnn_init(int* __restrict__ pcur, int* __restrict__ ticket,
                                                float* __restrict__ ge,
                                                const float* __restrict__ iv, const int* __restrict__ vvs,
                                                float* __restrict__ out) {
  const int tid = threadIdx.x;
  if (blockIdx.x == 0) {
    if (tid < 128) pcur[tid] = tid * CAPP;
    if (tid == 128) *ticket = 0;
    for (int i = tid; i < NB * H; i += 256) ge[i] = 0.f;
  } else {
    __shared__ float s[256];
    int b = blockIdx.x - 1;
    float v = iv[b * 256 + tid] * (float)vvs[(long)b * PP + tid];
    s[tid] = v; __syncthreads();
    for (int off = 128; off > 0; off >>= 1) {
      if (tid < off) s[tid] += s[tid + off];
      __syncthreads();
    }
    if (tid == 0) out[b] = s[0];
  }
}

// Staged record: .x = src(17b)<<15 | round(ew*32768), .y = dst
#define B1_BLOCKS 256
#define B1_TILES  4
__global__ __launch_bounds__(256) void gnn_bin1(const int* __restrict__ src, const int* __restrict__ dst,
                                                const float* __restrict__ ew, int* __restrict__ pcur,
                                                uint2* __restrict__ stage) {
  __shared__ int hist[128];
  __shared__ int pbase[128];
  const int tid = threadIdx.x;
  for (int t = 0; t < B1_TILES; ++t) {
    if (tid < 128) hist[tid] = 0;
    __syncthreads();
    const int ebase = blockIdx.x * (B1_TILES * 2048) + t * 2048;
    int parts[8], ranks[8];
    uint2 recs[8];
#pragma unroll
    for (int i = 0; i < 8; ++i) {
      int e = ebase + i * 256 + tid;
      int d = dst[e];
      int s = src[e];
      float w = ew[e];
      int wq = (int)fminf(w * 32768.f + 0.5f, 32767.f);
      parts[i] = d >> 10;
      recs[i].x = ((unsigned)s << 15) | (unsigned)wq;
      recs[i].y = (unsigned)d;
      ranks[i] = atomicAdd(&hist[parts[i]], 1);
    }
    __syncthreads();
    if (tid < 128) {
      int c = hist[tid];
      pbase[tid] = c ? atomicAdd(&pcur[tid], c) : 0;
    }
    __syncthreads();
#pragma unroll
    for (int i = 0; i < 8; ++i)
      stage[pbase[parts[i]] + ranks[i]] = recs[i];
    __syncthreads();
  }
}

__global__ __launch_bounds__(256) void gnn_bin2(const uint2* __restrict__ stage,
                                                const int* __restrict__ pcur,
                                                int* __restrict__ rowptr,
                                                unsigned* __restrict__ epack) {
  __shared__ int h[1024];
  __shared__ int ws[256];
  __shared__ int pc[128];
  __shared__ int gb_s;
  const int tid = threadIdx.x;
  const int p = blockIdx.x;
  const int node0 = p << 10;
  const int s0 = p * CAPP;
  const int cnt = pcur[p] - s0;
#pragma unroll
  for (int i = 0; i < 4; ++i) h[i * 256 + tid] = 0;
  if (tid < 128) pc[tid] = pcur[tid] - tid * CAPP;
  __syncthreads();
  for (int r = tid; r < cnt; r += 256)
    atomicAdd(&h[(int)stage[s0 + r].y - node0], 1);
  if (tid == 0) {
    int s = 0;
    for (int i = 0; i < p; ++i) s += pc[i];
    gb_s = s;
  }
  __syncthreads();
  const int gbase = gb_s;
  int a0 = h[tid * 4 + 0], a1 = h[tid * 4 + 1], a2 = h[tid * 4 + 2], a3 = h[tid * 4 + 3];
  int s1 = a0 + a1, s2 = s1 + a2, s3 = s2 + a3;
  ws[tid] = s3;
  __syncthreads();
  for (int o = 1; o < 256; o <<= 1) {
    int u = (tid >= o) ? ws[tid - o] : 0;
    __syncthreads();
    ws[tid] += u;
    __syncthreads();
  }
  int eb = gbase + (tid ? ws[tid - 1] : 0);
  int4 rp;
  rp.x = eb; rp.y = eb + a0; rp.z = eb + s1; rp.w = eb + s2;
  *(int4*)(rowptr + node0 + tid * 4) = rp;
  h[tid * 4 + 0] = rp.x; h[tid * 4 + 1] = rp.y; h[tid * 4 + 2] = rp.z; h[tid * 4 + 3] = rp.w;
  if (p == 127 && tid == 255) rowptr[NODES] = EDGES;
  __syncthreads();
  for (int r = tid; r < cnt; r += 256) {
    uint2 q = stage[s0 + r];
    int pos = atomicAdd(&h[(int)q.y - node0], 1);
    epack[pos] = q.x;
  }
}

// ============================================================================
// bf16 / fp8 helpers
// ============================================================================
__device__ __forceinline__ unsigned gnn_pack2bf(float a, float b) {
  union { float f; unsigned u; } x, y; x.f = a; y.f = b;
  unsigned ua = (x.u + 0x7FFFu + ((x.u >> 16) & 1u)) >> 16;
  unsigned ub = (y.u + 0x7FFFu + ((y.u >> 16) & 1u)) >> 16;
  return ua | (ub << 16);
}

__device__ __forceinline__ u16 gnn_f2bf(float a) {
  union { float f; unsigned u; } x; x.f = a;
  return (u16)((x.u + 0x7FFFu + ((x.u >> 16) & 1u)) >> 16);
}

__device__ __forceinline__ float gnn_bf2f(u16 h) {
  union { unsigned u; float f; } x; x.u = ((unsigned)h) << 16; return x.f;
}

// OCP e4m3fn single-byte encode (HW convert, RNE+sat)
__device__ __forceinline__ unsigned char gnn_f2fp8(float v) {
  return (unsigned char)(__builtin_amdgcn_cvt_pk_fp8_f32(v, v, 0, false) & 0xFF);
}

// convert a dword holding 2 packed bf16 into 2 fp8 bytes inside dst half-word
// (word-select must be a compile-time constant -> template parameter)
template<bool HI>
__device__ __forceinline__ unsigned gnn_bf2fp8pk(unsigned pv, unsigned old) {
  union { unsigned u; float f; } lo, hi;
  lo.u = pv << 16; hi.u = pv & 0xFFFF0000u;
  return __builtin_amdgcn_cvt_pk_fp8_f32(lo.f, hi.f, old, HI);
}

__device__ __forceinline__ float gnn_sig(float x)  { return 1.f / (1.f + __expf(-x)); }
__device__ __forceinline__ float gnn_tanh(float x) { return 1.f - 2.f / (1.f + __expf(2.f * x)); }

// ============================================================================
// STANDALONE agg, fp8-input (round-5 proven: fetch floor halved). One
// 16-lane group per node; lane s gathers uint2 (8 fp8 cols); HW
// v_cvt_pk_f32_fp8 decode; one exact 2^-15 weight scale at end.
// ============================================================================
__global__ __launch_bounds__(256) void gnn_agg(const unsigned char* __restrict__ X8,
                                               const int* __restrict__ rowptr,
                                               const unsigned* __restrict__ epack,
                                               u16* __restrict__ T) {
  const int tid = threadIdx.x;
  const int wave = tid >> 6, lane = tid & 63;
  const int g = lane >> 4, s = lane & 15;
  const unsigned soff = (unsigned)(s << 3);     // byte offset within 128B fp8 row
  const int node = blockIdx.x * 16 + wave * 4 + g;
  const int e1 = rowptr[node + 1];
  const int e0 = rowptr[node];
  float acc[8];
#pragma unroll
  for (int c = 0; c < 8; ++c) acc[c] = 0.f;

  for (int it = e0; __any(it < e1); it += 8) {
    unsigned qv[8];
#pragma unroll
    for (int j = 0; j < 8; ++j) {
      int t = it + j;
      t = t < e1 ? t : e1 - 1;
      t = t < 0 ? 0 : t;
      qv[j] = epack[t];
    }
    uint2 pv[8];
#pragma unroll
    for (int j = 0; j < 8; ++j)
      pv[j] = *(const uint2*)(X8 + ((((qv[j] >> 15) << 7)) | soff));
#pragma unroll
    for (int j = 0; j < 8; ++j) {
      float w = (it + j) < e1 ? (float)(qv[j] & 0x7FFFu) : 0.f;
      f32x2 f01 = __builtin_amdgcn_cvt_pk_f32_fp8(pv[j].x, false);
      f32x2 f23 = __builtin_amdgcn_cvt_pk_f32_fp8(pv[j].x, true);
      f32x2 f45 = __builtin_amdgcn_cvt_pk_f32_fp8(pv[j].y, false);
      f32x2 f67 = __builtin_amdgcn_cvt_pk_f32_fp8(pv[j].y, true);
      acc[0] = fmaf(w, f01.x, acc[0]);  acc[1] = fmaf(w, f01.y, acc[1]);
      acc[2] = fmaf(w, f23.x, acc[2]);  acc[3] = fmaf(w, f23.y, acc[3]);
      acc[4] = fmaf(w, f45.x, acc[4]);  acc[5] = fmaf(w, f45.y, acc[5]);
      acc[6] = fmaf(w, f67.x, acc[6]);  acc[7] = fmaf(w, f67.y, acc[7]);
    }
  }

  const float sc = 1.f / 32768.f;
  uint4 o;
  o.x = gnn_pack2bf(acc[0] * sc, acc[1] * sc);
  o.y = gnn_pack2bf(acc[2] * sc, acc[3] * sc);
  o.z = gnn_pack2bf(acc[4] * sc, acc[5] * sc);
  o.w = gnn_pack2bf(acc[6] * sc, acc[7] * sc);
  *(uint4*)(T + (long)node * H + s * 8) = o;
}

// ============================================================================
// weight prep (merged): Wc[l] = W[l] @ wi.T  (blocks 0..511)
//                       whT   = wh.T         (blocks 512..767)
// ============================================================================
__global__ __launch_bounds__(384) void gnn_prep(const float* __restrict__ c1W, const float* __restrict__ c1wi,
                                                const float* __restrict__ c2W, const float* __restrict__ c2wi,
                                                const float* __restrict__ wh1, const float* __restrict__ wh2,
                                                float* __restrict__ Wc, float* __restrict__ whT) {
  if (blockIdx.x < 512) {
    __shared__ float wrow[128];
    int l = blockIdx.x >> 7, k = blockIdx.x & 127, j = threadIdx.x;
    const float* Wl = (l < 2 ? c1W : c2W) + (l & 1) * 128 * 128;
    const float* wi = l < 2 ? c1wi : c2wi;
    if (j < 128) wrow[j] = Wl[k * 128 + j];
    __syncthreads();
    float acc = 0.f;
    for (int m = 0; m < 128; ++m) acc = fmaf(wrow[m], wi[j * 128 + m], acc);
    Wc[(long)l * 49152 + k * 384 + j] = acc;
  } else {
    int bb = blockIdx.x - 512;
    int c = bb >> 7, k = bb & 127, j = threadIdx.x;
    const float* wh = c ? wh2 : wh1;
    whT[((long)c * 128 + k) * 384 + j] = wh[j * 128 + k];
  }
}

// ============================================================================
// MFMA fragment plumbing
// A-frag (16x16x32): A[m=lane&15][k=(lane>>4)*8+j]; B[k][n=lane&15]
// C/D: col=lane&15, row=(lane>>4)*4+reg
// LDS A staging (ROWS=64 or 32): slot(ktq,row) = ktq*ROWS + (row ^ (ktq&7))
// ============================================================================
template<int K>
__device__ __forceinline__ void gnn_stage_bf(const u16* __restrict__ A, long row0,
                                             u16* lds, int tid) {
  constexpr int CH = K / 8;
#pragma unroll
  for (int it = 0; it < (64 * CH) / 256; ++it) {
    int c = it * 256 + tid;
    int row = c / CH, ktq = c % CH;
    uint4 v = *(const uint4*)(A + (row0 + row) * K + ktq * 8);
    int slot = ktq * 64 + (row ^ (ktq & 7));
    *(uint4*)(lds + slot * 8) = v;
  }
}

// 32-row variant (mgru): 2 chunks/thread
template<int K>
__device__ __forceinline__ void gnn_stage32(const u16* __restrict__ A, long row0,
                                            u16* lds, int tid) {
  constexpr int CH = K / 8;
#pragma unroll
  for (int it = 0; it < (32 * CH) / 256; ++it) {
    int c = it * 256 + tid;
    int row = c / CH, ktq = c % CH;
    uint4 v = *(const uint4*)(A + (row0 + row) * K + ktq * 8);
    int slot = ktq * 32 + (row ^ (ktq & 7));
    *(uint4*)(lds + slot * 8) = v;
  }
}

__device__ __forceinline__ bf16x8 gnn_afrag(const u16* lds, int rt, int ktq, int l16) {
  int slot = ktq * 64 + ((rt * 16 + l16) ^ (ktq & 7));
  return *(const bf16x8*)(lds + slot * 8);
}

__device__ __forceinline__ bf16x8 gnn_afrag32(const u16* lds, int rt, int ktq, int l16) {
  int slot = ktq * 32 + ((rt * 16 + l16) ^ (ktq & 7));
  return *(const bf16x8*)(lds + slot * 8);
}

__device__ __forceinline__ bf16x8 gnn_bfrag(const u16* __restrict__ pk,
                                            int ct, int kt, int KT, int lane) {
  return *(const bf16x8*)(pk + (((long)(ct * KT + kt)) * 64 + lane) * 8);
}

// scalar access of a C-layout element in A-layout LDS (64-row tiles)
__device__ __forceinline__ void gnn_lds_put(u16* lds, int row, int col, float v) {
  int kq = col >> 3, of = col & 7;
  lds[(kq * 64 + (row ^ (kq & 7))) * 8 + of] = gnn_f2bf(v);
}

__device__ __forceinline__ float gnn_lds_get(const u16* lds, int row, int col) {
  int kq = col >> 3, of = col & 7;
  return gnn_bf2f(lds[(kq * 64 + (row ^ (kq & 7))) * 8 + of]);
}

// 32-row variant
__device__ __forceinline__ float gnn_lds_get32(const u16* lds, int row, int col) {
  int kq = col >> 3, of = col & 7;
  return gnn_bf2f(lds[(kq * 32 + (row ^ (kq & 7))) * 8 + of]);
}

// ============================================================================
// weight packing to MFMA B-frag bf16 (one merged kernel)
// ============================================================================
__device__ __forceinline__ void gnn_pack_body(const float* __restrict__ W0, const float* __restrict__ W1,
                                              int ksplit, int LD, int coff, int KT, int b, int lane,
                                              u16* __restrict__ dst) {
  int kt = b % KT, ct = b / KT;
  int col = ct * 16 + (lane & 15) + coff;
  int kb = kt * 32 + ((lane >> 4) & 3) * 8;
  u16 h[8];
#pragma unroll
  for (int j = 0; j < 8; ++j) {
    int k = kb + j;
    float v = (k < ksplit) ? W0[(long)k * LD + col] : W1[(long)(k - ksplit) * LD + col];
    h[j] = gnn_f2bf(v);
  }
  uint4 o;
  o.x = (unsigned)h[0] | ((unsigned)h[1] << 16);
  o.y = (unsigned)h[2] | ((unsigned)h[3] << 16);
  o.z = (unsigned)h[4] | ((unsigned)h[5] << 16);
  o.w = (unsigned)h[6] | ((unsigned)h[7] << 16);
  ((uint4*)dst)[(long)b * 64 + lane] = o;
}

// 4 conv layers x (rz 128 + ai 32 + ah 32) = 768 blocks, then
// pe2(32) pg1(32) pg2(32) pl1(64) pl2(64) = 224 blocks -> 992 total
__global__ __launch_bounds__(64) void gnn_pack(const float* __restrict__ Wc, const float* __restrict__ whT,
                                               const float* __restrict__ We2, const float* __restrict__ Wg1,
                                               const float* __restrict__ Wg2, const float* __restrict__ Wl1,
                                               const float* __restrict__ Wl2, u16* __restrict__ pk) {
  int lane = threadIdx.x;
  if (blockIdx.x < 768) {
    int l = blockIdx.x / 192, r = blockIdx.x % 192;
    const float* Wcl = Wc + (long)l * 49152;
    const float* whl = whT + (long)(l >> 1) * 49152;
    u16* base = pk + (long)l * LYRE;
    if (r < 128)      gnn_pack_body(Wcl, whl, 128, 384, 0,   8, r,       lane, base);
    else if (r < 160) gnn_pack_body(Wcl, Wcl, 128, 384, 256, 4, r - 128, lane, base + RZE);
    else              gnn_pack_body(whl, whl, 128, 384, 256, 4, r - 160, lane, base + RZE + AIE);
  } else {
    int b = blockIdx.x - 768;
    u16* pe2 = pk + 4 * LYRE;
    if (b < 32)       gnn_pack_body(We2, We2, 128, 128, 0, 4, b,       lane, pe2);
    else if (b < 64)  gnn_pack_body(Wg1, Wg1, 128, 128, 0, 4, b - 32,  lane, pe2 + 16384);
    else if (b < 96)  gnn_pack_body(Wg2, Wg2, 128, 128, 0, 4, b - 64,  lane, pe2 + 32768);
    else if (b < 160) gnn_pack_body(Wl1, Wl1, 128, 256, 0, 4, b - 96,  lane, pe2 + 49152);
    else              gnn_pack_body(Wl2, Wl2, 256, 128, 0, 8, b - 160, lane, pe2 + 81920);
  }
}

// ============================================================================
// FUSED emb1+emb2: xc = relu( relu(G@W1 + b1) @ pk2 + b2 ), +X8 shadow.
// ============================================================================
__global__ __launch_bounds__(256) void gnn_emb(const float* __restrict__ G, const float* __restrict__ W1,
                                               const float* __restrict__ b1,
                                               const u16* __restrict__ pk2, const float* __restrict__ b2,
                                               u16* __restrict__ C, unsigned char* __restrict__ C8) {
  __shared__ u16 As[64 * 128];       // 16KB, A-frag layout
  __shared__ float AsT[16][68];      // 4.25KB
  __shared__ float Ws[16][132];      // 8.25KB
  const int tid = threadIdx.x;
  const int lane = tid & 63, wave = tid >> 6;
  const int quad = lane >> 4, l16 = lane & 15;
  const long row0 = (long)blockIdx.x * 64;

  // ---- phase 1: emb1 (K=16) ----
  {
    const int lr  = tid >> 2;
    const int lk4 = (tid & 3) * 4;
    const int wk  = tid >> 4;
    const int wj4 = (tid & 15) * 4;
    float4 a = *(const float4*)(G + (row0 + lr) * 16 + lk4);
    AsT[lk4 + 0][lr] = a.x; AsT[lk4 + 1][lr] = a.y; AsT[lk4 + 2][lr] = a.z; AsT[lk4 + 3][lr] = a.w;
    float4 w0 = *(const float4*)(W1 + (long)wk * 128 + wj4);
    float4 w1 = *(const float4*)(W1 + (long)wk * 128 + 64 + wj4);
    *(float4*)(&Ws[wk][wj4]) = w0;
    *(float4*)(&Ws[wk][64 + wj4]) = w1;
    __syncthreads();

    const int tx = tid & 15, ty = tid >> 4;
    float acc0[16], acc1[16];
#pragma unroll
    for (int i = 0; i < 16; ++i) { acc0[i] = 0.f; acc1[i] = 0.f; }
#pragma unroll
    for (int k = 0; k < 16; ++k) {
      float4 av  = *(const float4*)(&AsT[k][ty * 4]);
      float4 wv0 = *(const float4*)(&Ws[k][tx * 4]);
      float4 wv1 = *(const float4*)(&Ws[k][64 + tx * 4]);
#pragma unroll
      for (int i = 0; i < 4; ++i) {
        float av_i = (i == 0) ? av.x : (i == 1) ? av.y : (i == 2) ? av.z : av.w;
        acc0[i * 4 + 0] = fmaf(av_i, wv0.x, acc0[i * 4 + 0]);
        acc0[i * 4 + 1] = fmaf(av_i, wv0.y, acc0[i * 4 + 1]);
        acc0[i * 4 + 2] = fmaf(av_i, wv0.z, acc0[i * 4 + 2]);
        acc0[i * 4 + 3] = fmaf(av_i, wv0.w, acc0[i * 4 + 3]);
        acc1[i * 4 + 0] = fmaf(av_i, wv1.x, acc1[i * 4 + 0]);
        acc1[i * 4 + 1] = fmaf(av_i, wv1.y, acc1[i * 4 + 1]);
        acc1[i * 4 + 2] = fmaf(av_i, wv1.z, acc1[i * 4 + 2]);
        acc1[i * 4 + 3] = fmaf(av_i, wv1.w, acc1[i * 4 + 3]);
      }
    }
#pragma unroll
    for (int i = 0; i < 4; ++i) {
      int row = ty * 4 + i;
#pragma unroll
      for (int j = 0; j < 4; ++j) {
        int c0 = tx * 4 + j;
        gnn_lds_put(As, row, c0,      fmaxf(acc0[i * 4 + j] + b1[c0], 0.f));
        gnn_lds_put(As, row, c0 + 64, fmaxf(acc1[i * 4 + j] + b1[c0 + 64], 0.f));
      }
    }
  }
  __syncthreads();

  // ---- phase 2: emb2 MFMA (K=128, N=128, CT=2) ----
  f32x4 zero4 = {0.f, 0.f, 0.f, 0.f};
  f32x4 acc[4][2];
#pragma unroll
  for (int rt = 0; rt < 4; ++rt)
#pragma unroll
    for (int ct = 0; ct < 2; ++ct) acc[rt][ct] = zero4;
#pragma unroll
  for (int kt = 0; kt < 4; ++kt) {
    int ktq = kt * 4 + quad;
    bf16x8 af[4];
#pragma unroll
    for (int rt = 0; rt < 4; ++rt) af[rt] = gnn_afrag(As, rt, ktq, l16);
#pragma unroll
    for (int ct = 0; ct < 2; ++ct) {
      bf16x8 bf = gnn_bfrag(pk2, wave * 2 + ct, kt, 4, lane);
#pragma unroll
      for (int rt = 0; rt < 4; ++rt)
        acc[rt][ct] = __builtin_amdgcn_mfma_f32_16x16x32_bf16(af[rt], bf, acc[rt][ct], 0, 0, 0);
    }
  }
#pragma unroll
  for (int ct = 0; ct < 2; ++ct) {
    int col = (wave * 2 + ct) * 16 + l16;
    float bv = b2[col];
#pragma unroll
    for (int rt = 0; rt < 4; ++rt) {
      long row = row0 + rt * 16 + quad * 4;
#pragma unroll
      for (int r = 0; r < 4; ++r) {
        float v = fmaxf(acc[rt][ct][r] + bv, 0.f);
        C[(row + r) * H + col] = gnn_f2bf(v);
        C8[(row + r) * H + col] = gnn_f2fp8(v);
      }
    }
  }
}

// ============================================================================
// MFMA GRU, 4-pass low-pressure form, 32-row blocks: Y = GRUCell(m=T@Wc, h=X)
// ============================================================================
#define OSTR 136   // u16 row stride of the output staging view of Ts

template<int RELU>
__global__ __launch_bounds__(256, 3) void gnn_mgru(const u16* __restrict__ T, const u16* __restrict__ X,
                                                   const u16* __restrict__ pkRZ,
                                                   const u16* __restrict__ pkAI,
                                                   const u16* __restrict__ pkAH,
                                                   const float* __restrict__ bi, const float* __restrict__ bh,
                                                   u16* __restrict__ Y,
                                                   unsigned char* __restrict__ Y8) {
  __shared__ u16 Ts[32 * OSTR];
  __shared__ u16 Xs[32 * 128];
  const int tid = threadIdx.x;
  const int lane = tid & 63, wave = tid >> 6;
  const int quad = lane >> 4, l16 = lane & 15;
  const long row0 = (long)blockIdx.x * 32;
  gnn_stage32<128>(T, row0, Ts, tid);
  gnn_stage32<128>(X, row0, Xs, tid);

  float brz[2], bzz[2], bin_[2], bhn[2];
#pragma unroll
  for (int c = 0; c < 2; ++c) {
    int col = (wave * 2 + c) * 16 + l16;
    brz[c]  = bi[col] + bh[col];
    bzz[c]  = bi[128 + col] + bh[128 + col];
    bin_[c] = bi[256 + col];
    bhn[c]  = bh[256 + col];
  }
  __syncthreads();

  f32x4 zero4 = {0.f, 0.f, 0.f, 0.f};
  f32x4 g1[2][2], g2[2][2];

  // ---- P1: rr = gi_r + gh_r ; r = sig(rr + brz) (into g1) ----
#pragma unroll
  for (int rt = 0; rt < 2; ++rt)
#pragma unroll
    for (int c = 0; c < 2; ++c) g1[rt][c] = zero4;
#pragma unroll
  for (int kt = 0; kt < 4; ++kt) {
    int ktq = kt * 4 + quad;
    bf16x8 tf[2], xf[2];
#pragma unroll
    for (int rt = 0; rt < 2; ++rt) { tf[rt] = gnn_afrag32(Ts, rt, ktq, l16); xf[rt] = gnn_afrag32(Xs, rt, ktq, l16); }
#pragma unroll
    for (int c = 0; c < 2; ++c) {
      int ct = wave * 2 + c;
      bf16x8 bRT = gnn_bfrag(pkRZ, ct, kt,     8, lane);
      bf16x8 bRX = gnn_bfrag(pkRZ, ct, kt + 4, 8, lane);
#pragma unroll
      for (int rt = 0; rt < 2; ++rt) {
        g1[rt][c] = __builtin_amdgcn_mfma_f32_16x16x32_bf16(tf[rt], bRT, g1[rt][c], 0, 0, 0);
        g1[rt][c] = __builtin_amdgcn_mfma_f32_16x16x32_bf16(xf[rt], bRX, g1[rt][c], 0, 0, 0);
      }
    }
  }
#pragma unroll
  for (int rt = 0; rt < 2; ++rt)
#pragma unroll
    for (int c = 0; c < 2; ++c)
#pragma unroll
      for (int r = 0; r < 4; ++r)
        g1[rt][c][r] = gnn_sig(g1[rt][c][r] + brz[c]);

  // ---- P2: g2 = gh_n (X only) ; t = r*(g2 + bhn) (into g1) ----
#pragma unroll
  for (int rt = 0; rt < 2; ++rt)
#pragma unroll
    for (int c = 0; c < 2; ++c) g2[rt][c] = zero4;
#pragma unroll
  for (int kt = 0; kt < 4; ++kt) {
    int ktq = kt * 4 + quad;
    bf16x8 xf[2];
#pragma unroll
    for (int rt = 0; rt < 2; ++rt) xf[rt] = gnn_afrag32(Xs, rt, ktq, l16);
#pragma unroll
    for (int c = 0; c < 2; ++c) {
      bf16x8 bAH = gnn_bfrag(pkAH, wave * 2 + c, kt, 4, lane);
#pragma unroll
      for (int rt = 0; rt < 2; ++rt)
        g2[rt][c] = __builtin_amdgcn_mfma_f32_16x16x32_bf16(xf[rt], bAH, g2[rt][c], 0, 0, 0);
    }
  }
#pragma unroll
  for (int rt = 0; rt < 2; ++rt)
#pragma unroll
    for (int c = 0; c < 2; ++c)
#pragma unroll
      for (int r = 0; r < 4; ++r)
        g1[rt][c][r] = g1[rt][c][r] * (g2[rt][c][r] + bhn[c]);

  // ---- P3: g2 = gi_n (T only) ; n = tanh(g2 + bin + t) (into g1) ----
#pragma unroll
  for (int rt = 0; rt < 2; ++rt)
#pragma unroll
    for (int c = 0; c < 2; ++c) g2[rt][c] = zero4;
#pragma unroll
  for (int kt = 0; kt < 4; ++kt) {
    int ktq = kt * 4 + quad;
    bf16x8 tf[2];
#pragma unroll
    for (int rt = 0; rt < 2; ++rt) tf[rt] = gnn_afrag32(Ts, rt, ktq, l16);
#pragma unroll
    for (int c = 0; c < 2; ++c) {
      bf16x8 bAI = gnn_bfrag(pkAI, wave * 2 + c, kt, 4, lane);
#pragma unroll
      for (int rt = 0; rt < 2; ++rt)
        g2[rt][c] = __builtin_amdgcn_mfma_f32_16x16x32_bf16(tf[rt], bAI, g2[rt][c], 0, 0, 0);
    }
  }
#pragma unroll
  for (int rt = 0; rt < 2; ++rt)
#pragma unroll
    for (int c = 0; c < 2; ++c)
#pragma unroll
      for (int r = 0; r < 4; ++r)
        g1[rt][c][r] = gnn_tanh(g2[rt][c][r] + bin_[c] + g1[rt][c][r]);

  // ---- P4: g2 = gi_z + gh_z ; z = sig(g2+bzz); y = (1-z)n + z*h ----
#pragma unroll
  for (int rt = 0; rt < 2; ++rt)
#pragma unroll
    for (int c = 0; c < 2; ++c) g2[rt][c] = zero4;
#pragma unroll
  for (int kt = 0; kt < 4; ++kt) {
    int ktq = kt * 4 + quad;
    bf16x8 tf[2], xf[2];
#pragma unroll
    for (int rt = 0; rt < 2; ++rt) { tf[rt] = gnn_afrag32(Ts, rt, ktq, l16); xf[rt] = gnn_afrag32(Xs, rt, ktq, l16); }
#pragma unroll
    for (int c = 0; c < 2; ++c) {
      int ct = wave * 2 + c;
      bf16x8 bZT = gnn_bfrag(pkRZ, 8 + ct, kt,     8, lane);
      bf16x8 bZX = gnn_bfrag(pkRZ, 8 + ct, kt + 4, 8, lane);
#pragma unroll
      for (int rt = 0; rt < 2; ++rt) {
        g2[rt][c] = __builtin_amdgcn_mfma_f32_16x16x32_bf16(tf[rt], bZT, g2[rt][c], 0, 0, 0);
        g2[rt][c] = __builtin_amdgcn_mfma_f32_16x16x32_bf16(xf[rt], bZX, g2[rt][c], 0, 0, 0);
      }
    }
  }

  // y into registers (reads Xs for h), then stage through Ts for coalesced out
  float yv[2][2][4];
#pragma unroll
  for (int rt = 0; rt < 2; ++rt)
#pragma unroll
    for (int c = 0; c < 2; ++c) {
      int col = (wave * 2 + c) * 16 + l16;
      int rowl = rt * 16 + quad * 4;
#pragma unroll
      for (int r = 0; r < 4; ++r) {
        float z = gnn_sig(g2[rt][c][r] + bzz[c]);
        float h = gnn_lds_get32(Xs, rowl + r, col);
        float v = (1.f - z) * g1[rt][c][r] + z * h;
        if (RELU) v = fmaxf(v, 0.f);
        yv[rt][c][r] = v;
      }
    }
  __syncthreads();   // all waves finished reading Ts A-frags
#pragma unroll
  for (int rt = 0; rt < 2; ++rt)
#pragma unroll
    for (int c = 0; c < 2; ++c) {
      int col = (wave * 2 + c) * 16 + l16;
      int rowl = rt * 16 + quad * 4;
#pragma unroll
      for (int r = 0; r < 4; ++r)
        Ts[(rowl + r) * OSTR + col] = gnn_f2bf(yv[rt][c][r]);
    }
  __syncthreads();
  {
    const int orow = tid >> 3;             // 32 rows, 8 threads/row
    const int oc = (tid & 7) * 16;         // 16 u16 per thread
    const u16* src = Ts + orow * OSTR + oc;
    uint4 a = *(const uint4*)(src);
    uint4 b = *(const uint4*)(src + 8);
    u16* yd = Y + (row0 + orow) * H + oc;
    *(uint4*)(yd) = a;
    *(uint4*)(yd + 8) = b;
    if (Y8) {
      uint4 o8;
      o8.x = gnn_bf2fp8pk<true>(a.y, gnn_bf2fp8pk<false>(a.x, 0));
      o8.y = gnn_bf2fp8pk<true>(a.w, gnn_bf2fp8pk<false>(a.z, 0));
      o8.z = gnn_bf2fp8pk<true>(b.y, gnn_bf2fp8pk<false>(b.x, 0));
      o8.w = gnn_bf2fp8pk<true>(b.w, gnn_bf2fp8pk<false>(b.z, 0));
      *(uint4*)(Y8 + (row0 + orow) * H + oc) = o8;
    }
  }
}

// ============================================================================
// FUSED g1+g2 (+pool +last-block gbias): C = (relu(A@pk1+b1))@pk2 + b2.
// Epilogue column-sums fp32 g2 output into ge[graph][col]; the LAST block
// (device-scope ticket) then computes gb[b] = bl1 + (ge[b]/4096) @ Wl1b for
// all graphs — removes the standalone gbias launch. ge reads use
// device-scope atomicAdd(p,0) (coherent across XCDs).
// ============================================================================
__global__ __launch_bounds__(256) void gnn_g1g2(const u16* __restrict__ A,
                                                const u16* __restrict__ pk1, const float* __restrict__ b1,
                                                const u16* __restrict__ pk2, const float* __restrict__ b2,
                                                u16* __restrict__ C, float* __restrict__ ge,
                                                int* __restrict__ ticket,
                                                const float* __restrict__ Wl1b, const float* __restrict__ bl1,
                                                float* __restrict__ gb) {
  __shared__ u16 As[64 * 128];
  __shared__ u16 Ys[64 * 128];
  const int tid = threadIdx.x;
  const int lane = tid & 63, wave = tid >> 6;
  const int quad = lane >> 4, l16 = lane & 15;
  const long row0 = (long)blockIdx.x * 64;
  gnn_stage_bf<128>(A, row0, As, tid);
  __syncthreads();

  f32x4 zero4 = {0.f, 0.f, 0.f, 0.f};
  f32x4 acc[4][2];
#pragma unroll
  for (int rt = 0; rt < 4; ++rt)
#pragma unroll
    for (int ct = 0; ct < 2; ++ct) acc[rt][ct] = zero4;
#pragma unroll
  for (int kt = 0; kt < 4; ++kt) {
    int ktq = kt * 4 + quad;
    bf16x8 af[4];
#pragma unroll
    for (int rt = 0; rt < 4; ++rt) af[rt] = gnn_afrag(As, rt, ktq, l16);
#pragma unroll
    for (int ct = 0; ct < 2; ++ct) {
      bf16x8 bf = gnn_bfrag(pk1, wave * 2 + ct, kt, 4, lane);
#pragma unroll
      for (int rt = 0; rt < 4; ++rt)
        acc[rt][ct] = __builtin_amdgcn_mfma_f32_16x16x32_bf16(af[rt], bf, acc[rt][ct], 0, 0, 0);
    }
  }
#pragma unroll
  for (int ct = 0; ct < 2; ++ct) {
    int col = (wave * 2 + ct) * 16 + l16;
    float bv = b1[col];
#pragma unroll
    for (int rt = 0; rt < 4; ++rt) {
      int rowl = rt * 16 + quad * 4;
#pragma unroll
      for (int r = 0; r < 4; ++r)
        gnn_lds_put(Ys, rowl + r, col, fmaxf(acc[rt][ct][r] + bv, 0.f));
    }
  }
  __syncthreads();

  f32x4 acc2[4][2];
#pragma unroll
  for (int rt = 0; rt < 4; ++rt)
#pragma unroll
    for (int ct = 0; ct < 2; ++ct) acc2[rt][ct] = zero4;
#pragma unroll
  for (int kt = 0; kt < 4; ++kt) {
    int ktq = kt * 4 + quad;
    bf16x8 af[4];
#pragma unroll
    for (int rt = 0; rt < 4; ++rt) af[rt] = gnn_afrag(Ys, rt, ktq, l16);
#pragma unroll
    for (int ct = 0; ct < 2; ++ct) {
      bf16x8 bf = gnn_bfrag(pk2, wave * 2 + ct, kt, 4, lane);
#pragma unroll
      for (int rt = 0; rt < 4; ++rt)
        acc2[rt][ct] = __builtin_amdgcn_mfma_f32_16x16x32_bf16(af[rt], bf, acc2[rt][ct], 0, 0, 0);
    }
  }
  float psum[2];
#pragma unroll
  for (int ct = 0; ct < 2; ++ct) {
    int col = (wave * 2 + ct) * 16 + l16;
    float bv = b2[col];
    float cs = 0.f;
#pragma unroll
    for (int rt = 0; rt < 4; ++rt) {
      long row = row0 + rt * 16 + quad * 4;
#pragma unroll
      for (int r = 0; r < 4; ++r) {
        float v = acc2[rt][ct][r] + bv;
        cs += v;
        C[(row + r) * H + col] = gnn_f2bf(v);
      }
    }
    psum[ct] = cs;
  }
  const int b = (int)(row0 >> 12);
#pragma unroll
  for (int ct = 0; ct < 2; ++ct) {
    float v = psum[ct];
    v += __shfl_xor(v, 16);
    v += __shfl_xor(v, 32);
    if (quad == 0) {
      int col = (wave * 2 + ct) * 16 + l16;
      atomicAdd(&ge[b * H + col], v);
    }
  }

  // ---- last-block gbias ----
  __threadfence();
  __syncthreads();
  __shared__ int lastflag;
  if (tid == 0) lastflag = (atomicAdd(ticket, 1) == (int)gridDim.x - 1) ? 1 : 0;
  __syncthreads();
  if (lastflag) {
    __shared__ float g[128];
    for (int bb = 0; bb < NB; ++bb) {
      if (tid < 128) g[tid] = atomicAdd(&ge[bb * H + tid], 0.f) * (1.f / 4096.f);
      __syncthreads();
      float acc3 = bl1[tid];
      for (int k = 0; k < 128; ++k) acc3 = fmaf(g[k], Wl1b[k * 256 + tid], acc3);
      gb[bb * 256 + tid] = acc3;
      __syncthreads();
    }
  }
}

// ============================================================================
// FUSED l1+l2+bound: u2 = relu( relu(A@pk1 + gb[graph])@pk2 + b2 ) consumed
// in-register: p[row] = dot(u2[row], wl3) + bl3; out[b] += sum_row p*dx.
// Eliminates the u2 store (32MB), the bound kernel's re-read (32MB) and a
// launch. dx[pp] = sol[0][n] - sol[m][n], rows with m==0 contribute 0.
// ============================================================================
__global__ __launch_bounds__(256) void gnn_l1l2(const u16* __restrict__ A,
                                                const u16* __restrict__ pk1, const float* __restrict__ gb,
                                                const u16* __restrict__ pk2, const float* __restrict__ b2,
                                                const float* __restrict__ wl3, const float* __restrict__ bl3,
                                                const int* __restrict__ vvs, float* __restrict__ out) {
  __shared__ u16 As[64 * 128];   // 16KB
  __shared__ u16 Us[64 * 256];   // 32KB
  __shared__ float rowsum[64];
  const int tid = threadIdx.x;
  const int lane = tid & 63, wave = tid >> 6;
  const int quad = lane >> 4, l16 = lane & 15;
  const long row0 = (long)blockIdx.x * 64;
  gnn_stage_bf<128>(A, row0, As, tid);
  if (tid < 64) rowsum[tid] = 0.f;
  __syncthreads();

  f32x4 zero4 = {0.f, 0.f, 0.f, 0.f};
  {
    f32x4 acc[4][4];
#pragma unroll
    for (int rt = 0; rt < 4; ++rt)
#pragma unroll
      for (int ct = 0; ct < 4; ++ct) acc[rt][ct] = zero4;
#pragma unroll
    for (int kt = 0; kt < 4; ++kt) {
      int ktq = kt * 4 + quad;
      bf16x8 af[4];
#pragma unroll
      for (int rt = 0; rt < 4; ++rt) af[rt] = gnn_afrag(As, rt, ktq, l16);
#pragma unroll
      for (int ct = 0; ct < 4; ++ct) {
        bf16x8 bf = gnn_bfrag(pk1, wave * 4 + ct, kt, 4, lane);
#pragma unroll
        for (int rt = 0; rt < 4; ++rt)
          acc[rt][ct] = __builtin_amdgcn_mfma_f32_16x16x32_bf16(af[rt], bf, acc[rt][ct], 0, 0, 0);
      }
    }
    const float* bp = gb + (row0 >> 12) * 256;
#pragma unroll
    for (int ct = 0; ct < 4; ++ct) {
      int col = (wave * 4 + ct) * 16 + l16;
      float bv = bp[col];
#pragma unroll
      for (int rt = 0; rt < 4; ++rt) {
        int rowl = rt * 16 + quad * 4;
#pragma unroll
        for (int r = 0; r < 4; ++r)
          gnn_lds_put(Us, rowl + r, col, fmaxf(acc[rt][ct][r] + bv, 0.f));
      }
    }
  }
  __syncthreads();

  f32x4 acc2[4][2];
#pragma unroll
  for (int rt = 0; rt < 4; ++rt)
#pragma unroll
    for (int ct = 0; ct < 2; ++ct) acc2[rt][ct] = zero4;
#pragma unroll
  for (int kt = 0; kt < 8; ++kt) {
    int ktq = kt * 4 + quad;
    bf16x8 af[4];
#pragma unroll
    for (int rt = 0; rt < 4; ++rt) af[rt] = gnn_afrag(Us, rt, ktq, l16);
#pragma unroll
    for (int ct = 0; ct < 2; ++ct) {
      bf16x8 bf = gnn_bfrag(pk2, wave * 2 + ct, kt, 8, lane);
#pragma unroll
      for (int rt = 0; rt < 4; ++rt)
        acc2[rt][ct] = __builtin_amdgcn_mfma_f32_16x16x32_bf16(af[rt], bf, acc2[rt][ct], 0, 0, 0);
    }
  }

  // ---- bound epilogue (u2 consumed in-register) ----
  const int b = (int)(row0 >> 12);
  float w3[2], bvv[2];
#pragma unroll
  for (int ct = 0; ct < 2; ++ct) {
    int col = (wave * 2 + ct) * 16 + l16;
    w3[ct] = wl3[col];
    bvv[ct] = b2[col];
  }
#pragma unroll
  for (int rt = 0; rt < 4; ++rt) {
#pragma unroll
    for (int r = 0; r < 4; ++r) {
      float part = fmaxf(acc2[rt][0][r] + bvv[0], 0.f) * w3[0]
                 + fmaxf(acc2[rt][1][r] + bvv[1], 0.f) * w3[1];
      part += __shfl_xor(part, 1);
      part += __shfl_xor(part, 2);
      part += __shfl_xor(part, 4);
      part += __shfl_xor(part, 8);
      if (l16 == 0) atomicAdd(&rowsum[rt * 16 + quad * 4 + r], part);
    }
  }
  __syncthreads();
  if (tid < 64) {
    float p = rowsum[tid] + bl3[0];
    int pp = (int)(row0 & 4095) + tid;
    int m = pp >> 8, n = pp & 255;
    float contrib = 0.f;
    if (m != 0) {
      float dx = (float)(vvs[((long)b << 12) + n] - vvs[((long)b << 12) + pp]);
      contrib = p * dx;
    }
#pragma unroll
    for (int off = 32; off > 0; off >>= 1) contrib += __shfl_down(contrib, off);
    if (tid == 0) atomicAdd(&out[b], contrib);
  }
}

// ============================================================================
extern "C" void kernel_launch(void* const* d_in, const int* in_sizes, int n_in,
                              void* d_out, int out_size, void* d_ws, size_t ws_size,
                              hipStream_t stream) {
  const float* G      = (const float*)d_in[0];
  const int*   ei     = (const int*)d_in[1];
  const int*   esrc   = ei;
  const int*   edst   = ei + EDGES;
  const float* ew     = (const float*)d_in[2];
  const int*   vvs    = (const int*)d_in[4];
  const float* iv     = (const float*)d_in[5];
  const float* W_emb1 = (const float*)d_in[6];
  const float* b_emb1 = (const float*)d_in[7];
  const float* W_emb2 = (const float*)d_in[8];
  const float* b_emb2 = (const float*)d_in[9];
  const float* c1_W   = (const float*)d_in[10];
  const float* c1_wi  = (const float*)d_in[11];
  const float* c1_wh  = (const float*)d_in[12];
  const float* c1_bi  = (const float*)d_in[13];
  const float* c1_bh  = (const float*)d_in[14];
  const float* c2_W   = (const float*)d_in[15];
  const float* c2_wi  = (const float*)d_in[16];
  const float* c2_wh  = (const float*)d_in[17];
  const float* c2_bi  = (const float*)d_in[18];
  const float* c2_bh  = (const float*)d_in[19];
  const float* W_g1   = (const float*)d_in[20];
  const float* b_g1   = (const float*)d_in[21];
  const float* W_g2   = (const float*)d_in[22];
  const float* b_g2   = (const float*)d_in[23];
  const float* W_l1   = (const float*)d_in[24];
  const float* b_l1   = (const float*)d_in[25];
  const float* W_l2   = (const float*)d_in[26];
  const float* b_l2   = (const float*)d_in[27];
  const float* W_l3   = (const float*)d_in[28];
  const float* b_l3   = (const float*)d_in[29];
  float* out = (float*)d_out;
  (void)in_sizes; (void)n_in; (void)out_size; (void)ws_size;

  // ---- workspace carve (~120 MiB) ----
  char* wsb = (char*)d_ws;
  size_t off = 0;
  auto carve = [&](size_t bytes) -> char* {
    char* p = wsb + off;
    off += (bytes + 255) & ~(size_t)255;
    return p;
  };
  u16*   xa     = (u16*)carve(sizeof(u16) * (size_t)NODES * H);
  u16*   xc     = (u16*)carve(sizeof(u16) * (size_t)NODES * H);
  u16*   tb     = (u16*)carve(sizeof(u16) * (size_t)NODES * H);
  float* Wc     = (float*)carve(sizeof(float) * 4 * H * 384);
  float* whT    = (float*)carve(sizeof(float) * 2 * H * 384);
  u16*   pk     = (u16*)carve(sizeof(u16) * 507904);
  int*   rowptr = (int*)carve(sizeof(int) * (NODES + 1));
  int*   pcur   = (int*)carve(sizeof(int) * 128);
  int*   ticket = (int*)carve(sizeof(int) * 64);
  uint2* stage  = (uint2*)carve(sizeof(uint2) * (size_t)128 * CAPP);
  unsigned* epack = (unsigned*)carve(sizeof(unsigned) * EDGES);
  float* ge     = (float*)carve(sizeof(float) * NB * H);
  float* gb     = (float*)carve(sizeof(float) * NB * 256);

  // fp8 shadow of node features for agg gathers (16 MB), aliasing `stage`
  // (dead after bin2; producers fully overwrite before each agg consumes).
  unsigned char* X8 = (unsigned char*)stage;

  u16* pkRZ[4]; u16* pkAI[4]; u16* pkAH[4];
  for (int l = 0; l < 4; ++l) {
    pkRZ[l] = pk + (long)l * LYRE;
    pkAI[l] = pk + (long)l * LYRE + RZE;
    pkAH[l] = pk + (long)l * LYRE + RZE + AIE;
  }
  u16* pe2 = pk + 4 * LYRE;
  u16* pg1 = pe2 + 16384;
  u16* pg2 = pe2 + 32768;
  u16* pl1 = pe2 + 49152;
  u16* pl2 = pe2 + 81920;

  // ---- init (pcur + ticket + ge zero + item) ----
  gnn_init<<<NB + 1, 256, 0, stream>>>(pcur, ticket, ge, iv, vvs, out);

  // ---- CSR build ----
  gnn_bin1<<<B1_BLOCKS, 256, 0, stream>>>(esrc, edst, ew, pcur, stage);
  gnn_bin2<<<128, 256, 0, stream>>>(stage, pcur, rowptr, epack);

  // ---- weight prep + pack (merged) ----
  gnn_prep<<<768, 384, 0, stream>>>(c1_W, c1_wi, c2_W, c2_wi, c1_wh, c2_wh, Wc, whT);
  gnn_pack<<<992, 64, 0, stream>>>(Wc, whT, W_emb2, W_g1, W_g2, W_l1, W_l2, pk);

  // ---- embeddings fused: G -> xc (+X8) ----
  gnn_emb<<<NODES / 64, 256, 0, stream>>>(G, W_emb1, b_emb1, pe2, b_emb2, xc, X8);

  // ---- conv1: agg reads fp8 shadow; mgru writes next shadow ----
  gnn_agg<<<NODES / 16, 256, 0, stream>>>(X8, rowptr, epack, tb);
  gnn_mgru<0><<<NODES / 32, 256, 0, stream>>>(tb, xc, pkRZ[0], pkAI[0], pkAH[0], c1_bi, c1_bh, xa, X8);
  gnn_agg<<<NODES / 16, 256, 0, stream>>>(X8, rowptr, epack, tb);
  gnn_mgru<1><<<NODES / 32, 256, 0, stream>>>(tb, xa, pkRZ[1], pkAI[1], pkAH[1], c1_bi, c1_bh, xc, X8);

  // ---- conv2 ----
  gnn_agg<<<NODES / 16, 256, 0, stream>>>(X8, rowptr, epack, tb);
  gnn_mgru<0><<<NODES / 32, 256, 0, stream>>>(tb, xc, pkRZ[2], pkAI[2], pkAH[2], c2_bi, c2_bh, xa, X8);
  gnn_agg<<<NODES / 16, 256, 0, stream>>>(X8, rowptr, epack, tb);
  gnn_mgru<1><<<NODES / 32, 256, 0, stream>>>(tb, xa, pkRZ[3], pkAI[3], pkAH[3], c2_bi, c2_bh, xc, nullptr);

  // ---- head GEMMs fused (pool + last-block gbias): xc -> tb, ge, gb ----
  gnn_g1g2<<<NODES / 64, 256, 0, stream>>>(xc, pg1, b_g1, pg2, b_g2, tb, ge,
                                           ticket, W_l1 + 128 * 256, b_l1, gb);

  // ---- MLP fused l1+l2+bound: tb -> out ----
  gnn_l1l2<<<NODES / 64, 256, 0, stream>>>(tb, pl1, gb, pl2, b_l2, W_l3, b_l3, vvs, out);
}

// Round 13
// 689.587 us; speedup vs baseline: 1.4769x; 1.4769x over previous
//
#include <hip/hip_runtime.h>

#define NODES   131072
#define EDGES   2097152
#define H       128
#define NB      32        // graphs
#define PP      4096      // nodes per problem graph

typedef short bf16x8 __attribute__((ext_vector_type(8)));
typedef float f32x4  __attribute__((ext_vector_type(4)));
typedef float f32x2  __attribute__((ext_vector_type(2)));
typedef unsigned short u16;

// packed-weight element offsets
#define RZE 65536
#define AIE 16384
#define AHE 16384
#define LYRE (RZE + AIE + AHE)   // 98304 per conv layer

// ============================================================================
// INIT (1 launch): block 0 inits pcur + zeroes ge; blocks 1..32 compute
// item-value dot (out[b] = iv . sol[0]) — depends only on inputs; plain
// store precedes l1l2's bound atomics in stream order.
// ============================================================================
#define CAPP 18432

__global__ __launch_bounds__(256) void gnn_init(int* __restrict__ pcur,
                                                float* __restrict__ ge,
                                                const float* __restrict__ iv, const int* __restrict__ vvs,
                                                float* __restrict__ out) {
  const int tid = threadIdx.x;
  if (blockIdx.x == 0) {
    if (tid < 128) pcur[tid] = tid * CAPP;
    for (int i = tid; i < NB * H; i += 256) ge[i] = 0.f;
  } else {
    __shared__ float s[256];
    int b = blockIdx.x - 1;
    float v = iv[b * 256 + tid] * (float)vvs[(long)b * PP + tid];
    s[tid] = v; __syncthreads();
    for (int off = 128; off > 0; off >>= 1) {
      if (tid < off) s[tid] += s[tid + off];
      __syncthreads();
    }
    if (tid == 0) out[b] = s[0];
  }
}

// Staged record: .x = src(17b)<<15 | round(ew*32768), .y = dst
#define B1_BLOCKS 256
#define B1_TILES  4
__global__ __launch_bounds__(256) void gnn_bin1(const int* __restrict__ src, const int* __restrict__ dst,
                                                const float* __restrict__ ew, int* __restrict__ pcur,
                                                uint2* __restrict__ stage) {
  __shared__ int hist[128];
  __shared__ int pbase[128];
  const int tid = threadIdx.x;
  for (int t = 0; t < B1_TILES; ++t) {
    if (tid < 128) hist[tid] = 0;
    __syncthreads();
    const int ebase = blockIdx.x * (B1_TILES * 2048) + t * 2048;
    int parts[8], ranks[8];
    uint2 recs[8];
#pragma unroll
    for (int i = 0; i < 8; ++i) {
      int e = ebase + i * 256 + tid;
      int d = dst[e];
      int s = src[e];
      float w = ew[e];
      int wq = (int)fminf(w * 32768.f + 0.5f, 32767.f);
      parts[i] = d >> 10;
      recs[i].x = ((unsigned)s << 15) | (unsigned)wq;
      recs[i].y = (unsigned)d;
      ranks[i] = atomicAdd(&hist[parts[i]], 1);
    }
    __syncthreads();
    if (tid < 128) {
      int c = hist[tid];
      pbase[tid] = c ? atomicAdd(&pcur[tid], c) : 0;
    }
    __syncthreads();
#pragma unroll
    for (int i = 0; i < 8; ++i)
      stage[pbase[parts[i]] + ranks[i]] = recs[i];
    __syncthreads();
  }
}

__global__ __launch_bounds__(256) void gnn_bin2(const uint2* __restrict__ stage,
                                                const int* __restrict__ pcur,
                                                int* __restrict__ rowptr,
                                                unsigned* __restrict__ epack) {
  __shared__ int h[1024];
  __shared__ int ws[256];
  __shared__ int pc[128];
  __shared__ int gb_s;
  const int tid = threadIdx.x;
  const int p = blockIdx.x;
  const int node0 = p << 10;
  const int s0 = p * CAPP;
  const int cnt = pcur[p] - s0;
#pragma unroll
  for (int i = 0; i < 4; ++i) h[i * 256 + tid] = 0;
  if (tid < 128) pc[tid] = pcur[tid] - tid * CAPP;
  __syncthreads();
  for (int r = tid; r < cnt; r += 256)
    atomicAdd(&h[(int)stage[s0 + r].y - node0], 1);
  if (tid == 0) {
    int s = 0;
    for (int i = 0; i < p; ++i) s += pc[i];
    gb_s = s;
  }
  __syncthreads();
  const int gbase = gb_s;
  int a0 = h[tid * 4 + 0], a1 = h[tid * 4 + 1], a2 = h[tid * 4 + 2], a3 = h[tid * 4 + 3];
  int s1 = a0 + a1, s2 = s1 + a2, s3 = s2 + a3;
  ws[tid] = s3;
  __syncthreads();
  for (int o = 1; o < 256; o <<= 1) {
    int u = (tid >= o) ? ws[tid - o] : 0;
    __syncthreads();
    ws[tid] += u;
    __syncthreads();
  }
  int eb = gbase + (tid ? ws[tid - 1] : 0);
  int4 rp;
  rp.x = eb; rp.y = eb + a0; rp.z = eb + s1; rp.w = eb + s2;
  *(int4*)(rowptr + node0 + tid * 4) = rp;
  h[tid * 4 + 0] = rp.x; h[tid * 4 + 1] = rp.y; h[tid * 4 + 2] = rp.z; h[tid * 4 + 3] = rp.w;
  if (p == 127 && tid == 255) rowptr[NODES] = EDGES;
  __syncthreads();
  for (int r = tid; r < cnt; r += 256) {
    uint2 q = stage[s0 + r];
    int pos = atomicAdd(&h[(int)q.y - node0], 1);
    epack[pos] = q.x;
  }
}

// ============================================================================
// bf16 / fp8 helpers
// ============================================================================
__device__ __forceinline__ unsigned gnn_pack2bf(float a, float b) {
  union { float f; unsigned u; } x, y; x.f = a; y.f = b;
  unsigned ua = (x.u + 0x7FFFu + ((x.u >> 16) & 1u)) >> 16;
  unsigned ub = (y.u + 0x7FFFu + ((y.u >> 16) & 1u)) >> 16;
  return ua | (ub << 16);
}

__device__ __forceinline__ u16 gnn_f2bf(float a) {
  union { float f; unsigned u; } x; x.f = a;
  return (u16)((x.u + 0x7FFFu + ((x.u >> 16) & 1u)) >> 16);
}

__device__ __forceinline__ float gnn_bf2f(u16 h) {
  union { unsigned u; float f; } x; x.u = ((unsigned)h) << 16; return x.f;
}

// OCP e4m3fn single-byte encode (HW convert, RNE+sat)
__device__ __forceinline__ unsigned char gnn_f2fp8(float v) {
  return (unsigned char)(__builtin_amdgcn_cvt_pk_fp8_f32(v, v, 0, false) & 0xFF);
}

// convert a dword holding 2 packed bf16 into 2 fp8 bytes inside dst half-word
// (word-select must be a compile-time constant -> template parameter)
template<bool HI>
__device__ __forceinline__ unsigned gnn_bf2fp8pk(unsigned pv, unsigned old) {
  union { unsigned u; float f; } lo, hi;
  lo.u = pv << 16; hi.u = pv & 0xFFFF0000u;
  return __builtin_amdgcn_cvt_pk_fp8_f32(lo.f, hi.f, old, HI);
}

__device__ __forceinline__ float gnn_sig(float x)  { return 1.f / (1.f + __expf(-x)); }
__device__ __forceinline__ float gnn_tanh(float x) { return 1.f - 2.f / (1.f + __expf(2.f * x)); }

// ============================================================================
// STANDALONE agg, fp8-input (round-5 proven: fetch floor halved). One
// 16-lane group per node; lane s gathers uint2 (8 fp8 cols); HW
// v_cvt_pk_f32_fp8 decode; one exact 2^-15 weight scale at end.
// ============================================================================
__global__ __launch_bounds__(256) void gnn_agg(const unsigned char* __restrict__ X8,
                                               const int* __restrict__ rowptr,
                                               const unsigned* __restrict__ epack,
                                               u16* __restrict__ T) {
  const int tid = threadIdx.x;
  const int wave = tid >> 6, lane = tid & 63;
  const int g = lane >> 4, s = lane & 15;
  const unsigned soff = (unsigned)(s << 3);     // byte offset within 128B fp8 row
  const int node = blockIdx.x * 16 + wave * 4 + g;
  const int e1 = rowptr[node + 1];
  const int e0 = rowptr[node];
  float acc[8];
#pragma unroll
  for (int c = 0; c < 8; ++c) acc[c] = 0.f;

  for (int it = e0; __any(it < e1); it += 8) {
    unsigned qv[8];
#pragma unroll
    for (int j = 0; j < 8; ++j) {
      int t = it + j;
      t = t < e1 ? t : e1 - 1;
      t = t < 0 ? 0 : t;
      qv[j] = epack[t];
    }
    uint2 pv[8];
#pragma unroll
    for (int j = 0; j < 8; ++j)
      pv[j] = *(const uint2*)(X8 + ((((qv[j] >> 15) << 7)) | soff));
#pragma unroll
    for (int j = 0; j < 8; ++j) {
      float w = (it + j) < e1 ? (float)(qv[j] & 0x7FFFu) : 0.f;
      f32x2 f01 = __builtin_amdgcn_cvt_pk_f32_fp8(pv[j].x, false);
      f32x2 f23 = __builtin_amdgcn_cvt_pk_f32_fp8(pv[j].x, true);
      f32x2 f45 = __builtin_amdgcn_cvt_pk_f32_fp8(pv[j].y, false);
      f32x2 f67 = __builtin_amdgcn_cvt_pk_f32_fp8(pv[j].y, true);
      acc[0] = fmaf(w, f01.x, acc[0]);  acc[1] = fmaf(w, f01.y, acc[1]);
      acc[2] = fmaf(w, f23.x, acc[2]);  acc[3] = fmaf(w, f23.y, acc[3]);
      acc[4] = fmaf(w, f45.x, acc[4]);  acc[5] = fmaf(w, f45.y, acc[5]);
      acc[6] = fmaf(w, f67.x, acc[6]);  acc[7] = fmaf(w, f67.y, acc[7]);
    }
  }

  const float sc = 1.f / 32768.f;
  uint4 o;
  o.x = gnn_pack2bf(acc[0] * sc, acc[1] * sc);
  o.y = gnn_pack2bf(acc[2] * sc, acc[3] * sc);
  o.z = gnn_pack2bf(acc[4] * sc, acc[5] * sc);
  o.w = gnn_pack2bf(acc[6] * sc, acc[7] * sc);
  *(uint4*)(T + (long)node * H + s * 8) = o;
}

// ============================================================================
// weight prep (merged): Wc[l] = W[l] @ wi.T  (blocks 0..511)
//                       whT   = wh.T         (blocks 512..767)
// ============================================================================
__global__ __launch_bounds__(384) void gnn_prep(const float* __restrict__ c1W, const float* __restrict__ c1wi,
                                                const float* __restrict__ c2W, const float* __restrict__ c2wi,
                                                const float* __restrict__ wh1, const float* __restrict__ wh2,
                                                float* __restrict__ Wc, float* __restrict__ whT) {
  if (blockIdx.x < 512) {
    __shared__ float wrow[128];
    int l = blockIdx.x >> 7, k = blockIdx.x & 127, j = threadIdx.x;
    const float* Wl = (l < 2 ? c1W : c2W) + (l & 1) * 128 * 128;
    const float* wi = l < 2 ? c1wi : c2wi;
    if (j < 128) wrow[j] = Wl[k * 128 + j];
    __syncthreads();
    float acc = 0.f;
    for (int m = 0; m < 128; ++m) acc = fmaf(wrow[m], wi[j * 128 + m], acc);
    Wc[(long)l * 49152 + k * 384 + j] = acc;
  } else {
    int bb = blockIdx.x - 512;
    int c = bb >> 7, k = bb & 127, j = threadIdx.x;
    const float* wh = c ? wh2 : wh1;
    whT[((long)c * 128 + k) * 384 + j] = wh[j * 128 + k];
  }
}

// ============================================================================
// MFMA fragment plumbing
// A-frag (16x16x32): A[m=lane&15][k=(lane>>4)*8+j]; B[k][n=lane&15]
// C/D: col=lane&15, row=(lane>>4)*4+reg
// LDS A staging (ROWS=64 or 32): slot(ktq,row) = ktq*ROWS + (row ^ (ktq&7))
// ============================================================================
template<int K>
__device__ __forceinline__ void gnn_stage_bf(const u16* __restrict__ A, long row0,
                                             u16* lds, int tid) {
  constexpr int CH = K / 8;
#pragma unroll
  for (int it = 0; it < (64 * CH) / 256; ++it) {
    int c = it * 256 + tid;
    int row = c / CH, ktq = c % CH;
    uint4 v = *(const uint4*)(A + (row0 + row) * K + ktq * 8);
    int slot = ktq * 64 + (row ^ (ktq & 7));
    *(uint4*)(lds + slot * 8) = v;
  }
}

// 32-row variant (mgru): 2 chunks/thread
template<int K>
__device__ __forceinline__ void gnn_stage32(const u16* __restrict__ A, long row0,
                                            u16* lds, int tid) {
  constexpr int CH = K / 8;
#pragma unroll
  for (int it = 0; it < (32 * CH) / 256; ++it) {
    int c = it * 256 + tid;
    int row = c / CH, ktq = c % CH;
    uint4 v = *(const uint4*)(A + (row0 + row) * K + ktq * 8);
    int slot = ktq * 32 + (row ^ (ktq & 7));
    *(uint4*)(lds + slot * 8) = v;
  }
}

__device__ __forceinline__ bf16x8 gnn_afrag(const u16* lds, int rt, int ktq, int l16) {
  int slot = ktq * 64 + ((rt * 16 + l16) ^ (ktq & 7));
  return *(const bf16x8*)(lds + slot * 8);
}

__device__ __forceinline__ bf16x8 gnn_afrag32(const u16* lds, int rt, int ktq, int l16) {
  int slot = ktq * 32 + ((rt * 16 + l16) ^ (ktq & 7));
  return *(const bf16x8*)(lds + slot * 8);
}

__device__ __forceinline__ bf16x8 gnn_bfrag(const u16* __restrict__ pk,
                                            int ct, int kt, int KT, int lane) {
  return *(const bf16x8*)(pk + (((long)(ct * KT + kt)) * 64 + lane) * 8);
}

// scalar access of a C-layout element in A-layout LDS (64-row tiles)
__device__ __forceinline__ void gnn_lds_put(u16* lds, int row, int col, float v) {
  int kq = col >> 3, of = col & 7;
  lds[(kq * 64 + (row ^ (kq & 7))) * 8 + of] = gnn_f2bf(v);
}

__device__ __forceinline__ float gnn_lds_get(const u16* lds, int row, int col) {
  int kq = col >> 3, of = col & 7;
  return gnn_bf2f(lds[(kq * 64 + (row ^ (kq & 7))) * 8 + of]);
}

// 32-row variant
__device__ __forceinline__ float gnn_lds_get32(const u16* lds, int row, int col) {
  int kq = col >> 3, of = col & 7;
  return gnn_bf2f(lds[(kq * 32 + (row ^ (kq & 7))) * 8 + of]);
}

// ============================================================================
// weight packing to MFMA B-frag bf16 (one merged kernel)
// ============================================================================
__device__ __forceinline__ void gnn_pack_body(const float* __restrict__ W0, const float* __restrict__ W1,
                                              int ksplit, int LD, int coff, int KT, int b, int lane,
                                              u16* __restrict__ dst) {
  int kt = b % KT, ct = b / KT;
  int col = ct * 16 + (lane & 15) + coff;
  int kb = kt * 32 + ((lane >> 4) & 3) * 8;
  u16 h[8];
#pragma unroll
  for (int j = 0; j < 8; ++j) {
    int k = kb + j;
    float v = (k < ksplit) ? W0[(long)k * LD + col] : W1[(long)(k - ksplit) * LD + col];
    h[j] = gnn_f2bf(v);
  }
  uint4 o;
  o.x = (unsigned)h[0] | ((unsigned)h[1] << 16);
  o.y = (unsigned)h[2] | ((unsigned)h[3] << 16);
  o.z = (unsigned)h[4] | ((unsigned)h[5] << 16);
  o.w = (unsigned)h[6] | ((unsigned)h[7] << 16);
  ((uint4*)dst)[(long)b * 64 + lane] = o;
}

// 4 conv layers x (rz 128 + ai 32 + ah 32) = 768 blocks, then
// pe2(32) pg1(32) pg2(32) pl1(64) pl2(64) = 224 blocks -> 992 total
__global__ __launch_bounds__(64) void gnn_pack(const float* __restrict__ Wc, const float* __restrict__ whT,
                                               const float* __restrict__ We2, const float* __restrict__ Wg1,
                                               const float* __restrict__ Wg2, const float* __restrict__ Wl1,
                                               const float* __restrict__ Wl2, u16* __restrict__ pk) {
  int lane = threadIdx.x;
  if (blockIdx.x < 768) {
    int l = blockIdx.x / 192, r = blockIdx.x % 192;
    const float* Wcl = Wc + (long)l * 49152;
    const float* whl = whT + (long)(l >> 1) * 49152;
    u16* base = pk + (long)l * LYRE;
    if (r < 128)      gnn_pack_body(Wcl, whl, 128, 384, 0,   8, r,       lane, base);
    else if (r < 160) gnn_pack_body(Wcl, Wcl, 128, 384, 256, 4, r - 128, lane, base + RZE);
    else              gnn_pack_body(whl, whl, 128, 384, 256, 4, r - 160, lane, base + RZE + AIE);
  } else {
    int b = blockIdx.x - 768;
    u16* pe2 = pk + 4 * LYRE;
    if (b < 32)       gnn_pack_body(We2, We2, 128, 128, 0, 4, b,       lane, pe2);
    else if (b < 64)  gnn_pack_body(Wg1, Wg1, 128, 128, 0, 4, b - 32,  lane, pe2 + 16384);
    else if (b < 96)  gnn_pack_body(Wg2, Wg2, 128, 128, 0, 4, b - 64,  lane, pe2 + 32768);
    else if (b < 160) gnn_pack_body(Wl1, Wl1, 128, 256, 0, 4, b - 96,  lane, pe2 + 49152);
    else              gnn_pack_body(Wl2, Wl2, 256, 128, 0, 8, b - 160, lane, pe2 + 81920);
  }
}

// ============================================================================
// FUSED emb1+emb2: xc = relu( relu(G@W1 + b1) @ pk2 + b2 ), +X8 shadow.
// ============================================================================
__global__ __launch_bounds__(256) void gnn_emb(const float* __restrict__ G, const float* __restrict__ W1,
                                               const float* __restrict__ b1,
                                               const u16* __restrict__ pk2, const float* __restrict__ b2,
                                               u16* __restrict__ C, unsigned char* __restrict__ C8) {
  __shared__ u16 As[64 * 128];       // 16KB, A-frag layout
  __shared__ float AsT[16][68];      // 4.25KB
  __shared__ float Ws[16][132];      // 8.25KB
  const int tid = threadIdx.x;
  const int lane = tid & 63, wave = tid >> 6;
  const int quad = lane >> 4, l16 = lane & 15;
  const long row0 = (long)blockIdx.x * 64;

  // ---- phase 1: emb1 (K=16) ----
  {
    const int lr  = tid >> 2;
    const int lk4 = (tid & 3) * 4;
    const int wk  = tid >> 4;
    const int wj4 = (tid & 15) * 4;
    float4 a = *(const float4*)(G + (row0 + lr) * 16 + lk4);
    AsT[lk4 + 0][lr] = a.x; AsT[lk4 + 1][lr] = a.y; AsT[lk4 + 2][lr] = a.z; AsT[lk4 + 3][lr] = a.w;
    float4 w0 = *(const float4*)(W1 + (long)wk * 128 + wj4);
    float4 w1 = *(const float4*)(W1 + (long)wk * 128 + 64 + wj4);
    *(float4*)(&Ws[wk][wj4]) = w0;
    *(float4*)(&Ws[wk][64 + wj4]) = w1;
    __syncthreads();

    const int tx = tid & 15, ty = tid >> 4;
    float acc0[16], acc1[16];
#pragma unroll
    for (int i = 0; i < 16; ++i) { acc0[i] = 0.f; acc1[i] = 0.f; }
#pragma unroll
    for (int k = 0; k < 16; ++k) {
      float4 av  = *(const float4*)(&AsT[k][ty * 4]);
      float4 wv0 = *(const float4*)(&Ws[k][tx * 4]);
      float4 wv1 = *(const float4*)(&Ws[k][64 + tx * 4]);
#pragma unroll
      for (int i = 0; i < 4; ++i) {
        float av_i = (i == 0) ? av.x : (i == 1) ? av.y : (i == 2) ? av.z : av.w;
        acc0[i * 4 + 0] = fmaf(av_i, wv0.x, acc0[i * 4 + 0]);
        acc0[i * 4 + 1] = fmaf(av_i, wv0.y, acc0[i * 4 + 1]);
        acc0[i * 4 + 2] = fmaf(av_i, wv0.z, acc0[i * 4 + 2]);
        acc0[i * 4 + 3] = fmaf(av_i, wv0.w, acc0[i * 4 + 3]);
        acc1[i * 4 + 0] = fmaf(av_i, wv1.x, acc1[i * 4 + 0]);
        acc1[i * 4 + 1] = fmaf(av_i, wv1.y, acc1[i * 4 + 1]);
        acc1[i * 4 + 2] = fmaf(av_i, wv1.z, acc1[i * 4 + 2]);
        acc1[i * 4 + 3] = fmaf(av_i, wv1.w, acc1[i * 4 + 3]);
      }
    }
#pragma unroll
    for (int i = 0; i < 4; ++i) {
      int row = ty * 4 + i;
#pragma unroll
      for (int j = 0; j < 4; ++j) {
        int c0 = tx * 4 + j;
        gnn_lds_put(As, row, c0,      fmaxf(acc0[i * 4 + j] + b1[c0], 0.f));
        gnn_lds_put(As, row, c0 + 64, fmaxf(acc1[i * 4 + j] + b1[c0 + 64], 0.f));
      }
    }
  }
  __syncthreads();

  // ---- phase 2: emb2 MFMA (K=128, N=128, CT=2) ----
  f32x4 zero4 = {0.f, 0.f, 0.f, 0.f};
  f32x4 acc[4][2];
#pragma unroll
  for (int rt = 0; rt < 4; ++rt)
#pragma unroll
    for (int ct = 0; ct < 2; ++ct) acc[rt][ct] = zero4;
#pragma unroll
  for (int kt = 0; kt < 4; ++kt) {
    int ktq = kt * 4 + quad;
    bf16x8 af[4];
#pragma unroll
    for (int rt = 0; rt < 4; ++rt) af[rt] = gnn_afrag(As, rt, ktq, l16);
#pragma unroll
    for (int ct = 0; ct < 2; ++ct) {
      bf16x8 bf = gnn_bfrag(pk2, wave * 2 + ct, kt, 4, lane);
#pragma unroll
      for (int rt = 0; rt < 4; ++rt)
        acc[rt][ct] = __builtin_amdgcn_mfma_f32_16x16x32_bf16(af[rt], bf, acc[rt][ct], 0, 0, 0);
    }
  }
#pragma unroll
  for (int ct = 0; ct < 2; ++ct) {
    int col = (wave * 2 + ct) * 16 + l16;
    float bv = b2[col];
#pragma unroll
    for (int rt = 0; rt < 4; ++rt) {
      long row = row0 + rt * 16 + quad * 4;
#pragma unroll
      for (int r = 0; r < 4; ++r) {
        float v = fmaxf(acc[rt][ct][r] + bv, 0.f);
        C[(row + r) * H + col] = gnn_f2bf(v);
        C8[(row + r) * H + col] = gnn_f2fp8(v);
      }
    }
  }
}

// ============================================================================
// MFMA GRU, 4-pass low-pressure form, 32-row blocks: Y = GRUCell(m=T@Wc, h=X)
// ============================================================================
#define OSTR 136   // u16 row stride of the output staging view of Ts

template<int RELU>
__global__ __launch_bounds__(256, 3) void gnn_mgru(const u16* __restrict__ T, const u16* __restrict__ X,
                                                   const u16* __restrict__ pkRZ,
                                                   const u16* __restrict__ pkAI,
                                                   const u16* __restrict__ pkAH,
                                                   const float* __restrict__ bi, const float* __restrict__ bh,
                                                   u16* __restrict__ Y,
                                                   unsigned char* __restrict__ Y8) {
  __shared__ u16 Ts[32 * OSTR];
  __shared__ u16 Xs[32 * 128];
  const int tid = threadIdx.x;
  const int lane = tid & 63, wave = tid >> 6;
  const int quad = lane >> 4, l16 = lane & 15;
  const long row0 = (long)blockIdx.x * 32;
  gnn_stage32<128>(T, row0, Ts, tid);
  gnn_stage32<128>(X, row0, Xs, tid);

  float brz[2], bzz[2], bin_[2], bhn[2];
#pragma unroll
  for (int c = 0; c < 2; ++c) {
    int col = (wave * 2 + c) * 16 + l16;
    brz[c]  = bi[col] + bh[col];
    bzz[c]  = bi[128 + col] + bh[128 + col];
    bin_[c] = bi[256 + col];
    bhn[c]  = bh[256 + col];
  }
  __syncthreads();

  f32x4 zero4 = {0.f, 0.f, 0.f, 0.f};
  f32x4 g1[2][2], g2[2][2];

  // ---- P1: rr = gi_r + gh_r ; r = sig(rr + brz) (into g1) ----
#pragma unroll
  for (int rt = 0; rt < 2; ++rt)
#pragma unroll
    for (int c = 0; c < 2; ++c) g1[rt][c] = zero4;
#pragma unroll
  for (int kt = 0; kt < 4; ++kt) {
    int ktq = kt * 4 + quad;
    bf16x8 tf[2], xf[2];
#pragma unroll
    for (int rt = 0; rt < 2; ++rt) { tf[rt] = gnn_afrag32(Ts, rt, ktq, l16); xf[rt] = gnn_afrag32(Xs, rt, ktq, l16); }
#pragma unroll
    for (int c = 0; c < 2; ++c) {
      int ct = wave * 2 + c;
      bf16x8 bRT = gnn_bfrag(pkRZ, ct, kt,     8, lane);
      bf16x8 bRX = gnn_bfrag(pkRZ, ct, kt + 4, 8, lane);
#pragma unroll
      for (int rt = 0; rt < 2; ++rt) {
        g1[rt][c] = __builtin_amdgcn_mfma_f32_16x16x32_bf16(tf[rt], bRT, g1[rt][c], 0, 0, 0);
        g1[rt][c] = __builtin_amdgcn_mfma_f32_16x16x32_bf16(xf[rt], bRX, g1[rt][c], 0, 0, 0);
      }
    }
  }
#pragma unroll
  for (int rt = 0; rt < 2; ++rt)
#pragma unroll
    for (int c = 0; c < 2; ++c)
#pragma unroll
      for (int r = 0; r < 4; ++r)
        g1[rt][c][r] = gnn_sig(g1[rt][c][r] + brz[c]);

  // ---- P2: g2 = gh_n (X only) ; t = r*(g2 + bhn) (into g1) ----
#pragma unroll
  for (int rt = 0; rt < 2; ++rt)
#pragma unroll
    for (int c = 0; c < 2; ++c) g2[rt][c] = zero4;
#pragma unroll
  for (int kt = 0; kt < 4; ++kt) {
    int ktq = kt * 4 + quad;
    bf16x8 xf[2];
#pragma unroll
    for (int rt = 0; rt < 2; ++rt) xf[rt] = gnn_afrag32(Xs, rt, ktq, l16);
#pragma unroll
    for (int c = 0; c < 2; ++c) {
      bf16x8 bAH = gnn_bfrag(pkAH, wave * 2 + c, kt, 4, lane);
#pragma unroll
      for (int rt = 0; rt < 2; ++rt)
        g2[rt][c] = __builtin_amdgcn_mfma_f32_16x16x32_bf16(xf[rt], bAH, g2[rt][c], 0, 0, 0);
    }
  }
#pragma unroll
  for (int rt = 0; rt < 2; ++rt)
#pragma unroll
    for (int c = 0; c < 2; ++c)
#pragma unroll
      for (int r = 0; r < 4; ++r)
        g1[rt][c][r] = g1[rt][c][r] * (g2[rt][c][r] + bhn[c]);

  // ---- P3: g2 = gi_n (T only) ; n = tanh(g2 + bin + t) (into g1) ----
#pragma unroll
  for (int rt = 0; rt < 2; ++rt)
#pragma unroll
    for (int c = 0; c < 2; ++c) g2[rt][c] = zero4;
#pragma unroll
  for (int kt = 0; kt < 4; ++kt) {
    int ktq = kt * 4 + quad;
    bf16x8 tf[2];
#pragma unroll
    for (int rt = 0; rt < 2; ++rt) tf[rt] = gnn_afrag32(Ts, rt, ktq, l16);
#pragma unroll
    for (int c = 0; c < 2; ++c) {
      bf16x8 bAI = gnn_bfrag(pkAI, wave * 2 + c, kt, 4, lane);
#pragma unroll
      for (int rt = 0; rt < 2; ++rt)
        g2[rt][c] = __builtin_amdgcn_mfma_f32_16x16x32_bf16(tf[rt], bAI, g2[rt][c], 0, 0, 0);
    }
  }
#pragma unroll
  for (int rt = 0; rt < 2; ++rt)
#pragma unroll
    for (int c = 0; c < 2; ++c)
#pragma unroll
      for (int r = 0; r < 4; ++r)
        g1[rt][c][r] = gnn_tanh(g2[rt][c][r] + bin_[c] + g1[rt][c][r]);

  // ---- P4: g2 = gi_z + gh_z ; z = sig(g2+bzz); y = (1-z)n + z*h ----
#pragma unroll
  for (int rt = 0; rt < 2; ++rt)
#pragma unroll
    for (int c = 0; c < 2; ++c) g2[rt][c] = zero4;
#pragma unroll
  for (int kt = 0; kt < 4; ++kt) {
    int ktq = kt * 4 + quad;
    bf16x8 tf[2], xf[2];
#pragma unroll
    for (int rt = 0; rt < 2; ++rt) { tf[rt] = gnn_afrag32(Ts, rt, ktq, l16); xf[rt] = gnn_afrag32(Xs, rt, ktq, l16); }
#pragma unroll
    for (int c = 0; c < 2; ++c) {
      int ct = wave * 2 + c;
      bf16x8 bZT = gnn_bfrag(pkRZ, 8 + ct, kt,     8, lane);
      bf16x8 bZX = gnn_bfrag(pkRZ, 8 + ct, kt + 4, 8, lane);
#pragma unroll
      for (int rt = 0; rt < 2; ++rt) {
        g2[rt][c] = __builtin_amdgcn_mfma_f32_16x16x32_bf16(tf[rt], bZT, g2[rt][c], 0, 0, 0);
        g2[rt][c] = __builtin_amdgcn_mfma_f32_16x16x32_bf16(xf[rt], bZX, g2[rt][c], 0, 0, 0);
      }
    }
  }

  // y into registers (reads Xs for h), then stage through Ts for coalesced out
  float yv[2][2][4];
#pragma unroll
  for (int rt = 0; rt < 2; ++rt)
#pragma unroll
    for (int c = 0; c < 2; ++c) {
      int col = (wave * 2 + c) * 16 + l16;
      int rowl = rt * 16 + quad * 4;
#pragma unroll
      for (int r = 0; r < 4; ++r) {
        float z = gnn_sig(g2[rt][c][r] + bzz[c]);
        float h = gnn_lds_get32(Xs, rowl + r, col);
        float v = (1.f - z) * g1[rt][c][r] + z * h;
        if (RELU) v = fmaxf(v, 0.f);
        yv[rt][c][r] = v;
      }
    }
  __syncthreads();   // all waves finished reading Ts A-frags
#pragma unroll
  for (int rt = 0; rt < 2; ++rt)
#pragma unroll
    for (int c = 0; c < 2; ++c) {
      int col = (wave * 2 + c) * 16 + l16;
      int rowl = rt * 16 + quad * 4;
#pragma unroll
      for (int r = 0; r < 4; ++r)
        Ts[(rowl + r) * OSTR + col] = gnn_f2bf(yv[rt][c][r]);
    }
  __syncthreads();
  {
    const int orow = tid >> 3;             // 32 rows, 8 threads/row
    const int oc = (tid & 7) * 16;         // 16 u16 per thread
    const u16* src = Ts + orow * OSTR + oc;
    uint4 a = *(const uint4*)(src);
    uint4 b = *(const uint4*)(src + 8);
    u16* yd = Y + (row0 + orow) * H + oc;
    *(uint4*)(yd) = a;
    *(uint4*)(yd + 8) = b;
    if (Y8) {
      uint4 o8;
      o8.x = gnn_bf2fp8pk<true>(a.y, gnn_bf2fp8pk<false>(a.x, 0));
      o8.y = gnn_bf2fp8pk<true>(a.w, gnn_bf2fp8pk<false>(a.z, 0));
      o8.z = gnn_bf2fp8pk<true>(b.y, gnn_bf2fp8pk<false>(b.x, 0));
      o8.w = gnn_bf2fp8pk<true>(b.w, gnn_bf2fp8pk<false>(b.z, 0));
      *(uint4*)(Y8 + (row0 + orow) * H + oc) = o8;
    }
  }
}

// ============================================================================
// FUSED g1+g2 (+pool): C = (relu(A@pk1+b1))@pk2 + b2  (both K=128, N=128)
// Epilogue column-sums the fp32 g2 output per block and atomicAdds into
// ge[graph][col]. (Round-12's last-block gbias fusion REVERTED: per-block
// device __threadfence across 2048 blocks serialized at the fabric,
// 20us -> 361us. gbias is a standalone launch again.)
// ============================================================================
__global__ __launch_bounds__(256) void gnn_g1g2(const u16* __restrict__ A,
                                                const u16* __restrict__ pk1, const float* __restrict__ b1,
                                                const u16* __restrict__ pk2, const float* __restrict__ b2,
                                                u16* __restrict__ C, float* __restrict__ ge) {
  __shared__ u16 As[64 * 128];
  __shared__ u16 Ys[64 * 128];
  const int tid = threadIdx.x;
  const int lane = tid & 63, wave = tid >> 6;
  const int quad = lane >> 4, l16 = lane & 15;
  const long row0 = (long)blockIdx.x * 64;
  gnn_stage_bf<128>(A, row0, As, tid);
  __syncthreads();

  f32x4 zero4 = {0.f, 0.f, 0.f, 0.f};
  f32x4 acc[4][2];
#pragma unroll
  for (int rt = 0; rt < 4; ++rt)
#pragma unroll
    for (int ct = 0; ct < 2; ++ct) acc[rt][ct] = zero4;
#pragma unroll
  for (int kt = 0; kt < 4; ++kt) {
    int ktq = kt * 4 + quad;
    bf16x8 af[4];
#pragma unroll
    for (int rt = 0; rt < 4; ++rt) af[rt] = gnn_afrag(As, rt, ktq, l16);
#pragma unroll
    for (int ct = 0; ct < 2; ++ct) {
      bf16x8 bf = gnn_bfrag(pk1, wave * 2 + ct, kt, 4, lane);
#pragma unroll
      for (int rt = 0; rt < 4; ++rt)
        acc[rt][ct] = __builtin_amdgcn_mfma_f32_16x16x32_bf16(af[rt], bf, acc[rt][ct], 0, 0, 0);
    }
  }
#pragma unroll
  for (int ct = 0; ct < 2; ++ct) {
    int col = (wave * 2 + ct) * 16 + l16;
    float bv = b1[col];
#pragma unroll
    for (int rt = 0; rt < 4; ++rt) {
      int rowl = rt * 16 + quad * 4;
#pragma unroll
      for (int r = 0; r < 4; ++r)
        gnn_lds_put(Ys, rowl + r, col, fmaxf(acc[rt][ct][r] + bv, 0.f));
    }
  }
  __syncthreads();

  f32x4 acc2[4][2];
#pragma unroll
  for (int rt = 0; rt < 4; ++rt)
#pragma unroll
    for (int ct = 0; ct < 2; ++ct) acc2[rt][ct] = zero4;
#pragma unroll
  for (int kt = 0; kt < 4; ++kt) {
    int ktq = kt * 4 + quad;
    bf16x8 af[4];
#pragma unroll
    for (int rt = 0; rt < 4; ++rt) af[rt] = gnn_afrag(Ys, rt, ktq, l16);
#pragma unroll
    for (int ct = 0; ct < 2; ++ct) {
      bf16x8 bf = gnn_bfrag(pk2, wave * 2 + ct, kt, 4, lane);
#pragma unroll
      for (int rt = 0; rt < 4; ++rt)
        acc2[rt][ct] = __builtin_amdgcn_mfma_f32_16x16x32_bf16(af[rt], bf, acc2[rt][ct], 0, 0, 0);
    }
  }
  float psum[2];
#pragma unroll
  for (int ct = 0; ct < 2; ++ct) {
    int col = (wave * 2 + ct) * 16 + l16;
    float bv = b2[col];
    float cs = 0.f;
#pragma unroll
    for (int rt = 0; rt < 4; ++rt) {
      long row = row0 + rt * 16 + quad * 4;
#pragma unroll
      for (int r = 0; r < 4; ++r) {
        float v = acc2[rt][ct][r] + bv;
        cs += v;
        C[(row + r) * H + col] = gnn_f2bf(v);
      }
    }
    psum[ct] = cs;
  }
  const int b = (int)(row0 >> 12);
#pragma unroll
  for (int ct = 0; ct < 2; ++ct) {
    float v = psum[ct];
    v += __shfl_xor(v, 16);
    v += __shfl_xor(v, 32);
    if (quad == 0) {
      int col = (wave * 2 + ct) * 16 + l16;
      atomicAdd(&ge[b * H + col], v);
    }
  }
}

// ============================================================================
// per-graph bias: gb[b] = bl1 + (ge[b]/4096) @ Wl1b
// ============================================================================
__global__ __launch_bounds__(256) void gnn_gbias(const float* __restrict__ ge, const float* __restrict__ Wl1b,
                                                 const float* __restrict__ bl1, float* __restrict__ gb) {
  __shared__ float g[128];
  int b = blockIdx.x, t = threadIdx.x;
  if (t < 128) g[t] = ge[b * H + t] * (1.f / 4096.f);
  __syncthreads();
  float acc = bl1[t];
  for (int k = 0; k < 128; ++k) acc = fmaf(g[k], Wl1b[k * 256 + t], acc);
  gb[b * 256 + t] = acc;
}

// ============================================================================
// FUSED l1+l2+bound: u2 = relu( relu(A@pk1 + gb[graph])@pk2 + b2 ) consumed
// in-register: p[row] = dot(u2[row], wl3) + bl3; out[b] += sum_row p*dx.
// ============================================================================
__global__ __launch_bounds__(256) void gnn_l1l2(const u16* __restrict__ A,
                                                const u16* __restrict__ pk1, const float* __restrict__ gb,
                                                const u16* __restrict__ pk2, const float* __restrict__ b2,
                                                const float* __restrict__ wl3, const float* __restrict__ bl3,
                                                const int* __restrict__ vvs, float* __restrict__ out) {
  __shared__ u16 As[64 * 128];   // 16KB
  __shared__ u16 Us[64 * 256];   // 32KB
  __shared__ float rowsum[64];
  const int tid = threadIdx.x;
  const int lane = tid & 63, wave = tid >> 6;
  const int quad = lane >> 4, l16 = lane & 15;
  const long row0 = (long)blockIdx.x * 64;
  gnn_stage_bf<128>(A, row0, As, tid);
  if (tid < 64) rowsum[tid] = 0.f;
  __syncthreads();

  f32x4 zero4 = {0.f, 0.f, 0.f, 0.f};
  {
    f32x4 acc[4][4];
#pragma unroll
    for (int rt = 0; rt < 4; ++rt)
#pragma unroll
      for (int ct = 0; ct < 4; ++ct) acc[rt][ct] = zero4;
#pragma unroll
    for (int kt = 0; kt < 4; ++kt) {
      int ktq = kt * 4 + quad;
      bf16x8 af[4];
#pragma unroll
      for (int rt = 0; rt < 4; ++rt) af[rt] = gnn_afrag(As, rt, ktq, l16);
#pragma unroll
      for (int ct = 0; ct < 4; ++ct) {
        bf16x8 bf = gnn_bfrag(pk1, wave * 4 + ct, kt, 4, lane);
#pragma unroll
        for (int rt = 0; rt < 4; ++rt)
          acc[rt][ct] = __builtin_amdgcn_mfma_f32_16x16x32_bf16(af[rt], bf, acc[rt][ct], 0, 0, 0);
      }
    }
    const float* bp = gb + (row0 >> 12) * 256;
#pragma unroll
    for (int ct = 0; ct < 4; ++ct) {
      int col = (wave * 4 + ct) * 16 + l16;
      float bv = bp[col];
#pragma unroll
      for (int rt = 0; rt < 4; ++rt) {
        int rowl = rt * 16 + quad * 4;
#pragma unroll
        for (int r = 0; r < 4; ++r)
          gnn_lds_put(Us, rowl + r, col, fmaxf(acc[rt][ct][r] + bv, 0.f));
      }
    }
  }
  __syncthreads();

  f32x4 acc2[4][2];
#pragma unroll
  for (int rt = 0; rt < 4; ++rt)
#pragma unroll
    for (int ct = 0; ct < 2; ++ct) acc2[rt][ct] = zero4;
#pragma unroll
  for (int kt = 0; kt < 8; ++kt) {
    int ktq = kt * 4 + quad;
    bf16x8 af[4];
#pragma unroll
    for (int rt = 0; rt < 4; ++rt) af[rt] = gnn_afrag(Us, rt, ktq, l16);
#pragma unroll
    for (int ct = 0; ct < 2; ++ct) {
      bf16x8 bf = gnn_bfrag(pk2, wave * 2 + ct, kt, 8, lane);
#pragma unroll
      for (int rt = 0; rt < 4; ++rt)
        acc2[rt][ct] = __builtin_amdgcn_mfma_f32_16x16x32_bf16(af[rt], bf, acc2[rt][ct], 0, 0, 0);
    }
  }

  // ---- bound epilogue (u2 consumed in-register) ----
  const int b = (int)(row0 >> 12);
  float w3[2], bvv[2];
#pragma unroll
  for (int ct = 0; ct < 2; ++ct) {
    int col = (wave * 2 + ct) * 16 + l16;
    w3[ct] = wl3[col];
    bvv[ct] = b2[col];
  }
#pragma unroll
  for (int rt = 0; rt < 4; ++rt) {
#pragma unroll
    for (int r = 0; r < 4; ++r) {
      float part = fmaxf(acc2[rt][0][r] + bvv[0], 0.f) * w3[0]
                 + fmaxf(acc2[rt][1][r] + bvv[1], 0.f) * w3[1];
      part += __shfl_xor(part, 1);
      part += __shfl_xor(part, 2);
      part += __shfl_xor(part, 4);
      part += __shfl_xor(part, 8);
      if (l16 == 0) atomicAdd(&rowsum[rt * 16 + quad * 4 + r], part);
    }
  }
  __syncthreads();
  if (tid < 64) {
    float p = rowsum[tid] + bl3[0];
    int pp = (int)(row0 & 4095) + tid;
    int m = pp >> 8, n = pp & 255;
    float contrib = 0.f;
    if (m != 0) {
      float dx = (float)(vvs[((long)b << 12) + n] - vvs[((long)b << 12) + pp]);
      contrib = p * dx;
    }
#pragma unroll
    for (int off = 32; off > 0; off >>= 1) contrib += __shfl_down(contrib, off);
    if (tid == 0) atomicAdd(&out[b], contrib);
  }
}

// ============================================================================
extern "C" void kernel_launch(void* const* d_in, const int* in_sizes, int n_in,
                              void* d_out, int out_size, void* d_ws, size_t ws_size,
                              hipStream_t stream) {
  const float* G      = (const float*)d_in[0];
  const int*   ei     = (const int*)d_in[1];
  const int*   esrc   = ei;
  const int*   edst   = ei + EDGES;
  const float* ew     = (const float*)d_in[2];
  const int*   vvs    = (const int*)d_in[4];
  const float* iv     = (const float*)d_in[5];
  const float* W_emb1 = (const float*)d_in[6];
  const float* b_emb1 = (const float*)d_in[7];
  const float* W_emb2 = (const float*)d_in[8];
  const float* b_emb2 = (const float*)d_in[9];
  const float* c1_W   = (const float*)d_in[10];
  const float* c1_wi  = (const float*)d_in[11];
  const float* c1_wh  = (const float*)d_in[12];
  const float* c1_bi  = (const float*)d_in[13];
  const float* c1_bh  = (const float*)d_in[14];
  const float* c2_W   = (const float*)d_in[15];
  const float* c2_wi  = (const float*)d_in[16];
  const float* c2_wh  = (const float*)d_in[17];
  const float* c2_bi  = (const float*)d_in[18];
  const float* c2_bh  = (const float*)d_in[19];
  const float* W_g1   = (const float*)d_in[20];
  const float* b_g1   = (const float*)d_in[21];
  const float* W_g2   = (const float*)d_in[22];
  const float* b_g2   = (const float*)d_in[23];
  const float* W_l1   = (const float*)d_in[24];
  const float* b_l1   = (const float*)d_in[25];
  const float* W_l2   = (const float*)d_in[26];
  const float* b_l2   = (const float*)d_in[27];
  const float* W_l3   = (const float*)d_in[28];
  const float* b_l3   = (const float*)d_in[29];
  float* out = (float*)d_out;
  (void)in_sizes; (void)n_in; (void)out_size; (void)ws_size;

  // ---- workspace carve (~120 MiB) ----
  char* wsb = (char*)d_ws;
  size_t off = 0;
  auto carve = [&](size_t bytes) -> char* {
    char* p = wsb + off;
    off += (bytes + 255) & ~(size_t)255;
    return p;
  };
  u16*   xa     = (u16*)carve(sizeof(u16) * (size_t)NODES * H);
  u16*   xc     = (u16*)carve(sizeof(u16) * (size_t)NODES * H);
  u16*   tb     = (u16*)carve(sizeof(u16) * (size_t)NODES * H);
  float* Wc     = (float*)carve(sizeof(float) * 4 * H * 384);
  float* whT    = (float*)carve(sizeof(float) * 2 * H * 384);
  u16*   pk     = (u16*)carve(sizeof(u16) * 507904);
  int*   rowptr = (int*)carve(sizeof(int) * (NODES + 1));
  int*   pcur   = (int*)carve(sizeof(int) * 128);
  uint2* stage  = (uint2*)carve(sizeof(uint2) * (size_t)128 * CAPP);
  unsigned* epack = (unsigned*)carve(sizeof(unsigned) * EDGES);
  float* ge     = (float*)carve(sizeof(float) * NB * H);
  float* gb     = (float*)carve(sizeof(float) * NB * 256);

  // fp8 shadow of node features for agg gathers (16 MB), aliasing `stage`
  // (dead after bin2; producers fully overwrite before each agg consumes).
  unsigned char* X8 = (unsigned char*)stage;

  u16* pkRZ[4]; u16* pkAI[4]; u16* pkAH[4];
  for (int l = 0; l < 4; ++l) {
    pkRZ[l] = pk + (long)l * LYRE;
    pkAI[l] = pk + (long)l * LYRE + RZE;
    pkAH[l] = pk + (long)l * LYRE + RZE + AIE;
  }
  u16* pe2 = pk + 4 * LYRE;
  u16* pg1 = pe2 + 16384;
  u16* pg2 = pe2 + 32768;
  u16* pl1 = pe2 + 49152;
  u16* pl2 = pe2 + 81920;

  // ---- init (pcur + ge zero + item) ----
  gnn_init<<<NB + 1, 256, 0, stream>>>(pcur, ge, iv, vvs, out);

  // ---- CSR build ----
  gnn_bin1<<<B1_BLOCKS, 256, 0, stream>>>(esrc, edst, ew, pcur, stage);
  gnn_bin2<<<128, 256, 0, stream>>>(stage, pcur, rowptr, epack);

  // ---- weight prep + pack (merged) ----
  gnn_prep<<<768, 384, 0, stream>>>(c1_W, c1_wi, c2_W, c2_wi, c1_wh, c2_wh, Wc, whT);
  gnn_pack<<<992, 64, 0, stream>>>(Wc, whT, W_emb2, W_g1, W_g2, W_l1, W_l2, pk);

  // ---- embeddings fused: G -> xc (+X8) ----
  gnn_emb<<<NODES / 64, 256, 0, stream>>>(G, W_emb1, b_emb1, pe2, b_emb2, xc, X8);

  // ---- conv1: agg reads fp8 shadow; mgru writes next shadow ----
  gnn_agg<<<NODES / 16, 256, 0, stream>>>(X8, rowptr, epack, tb);
  gnn_mgru<0><<<NODES / 32, 256, 0, stream>>>(tb, xc, pkRZ[0], pkAI[0], pkAH[0], c1_bi, c1_bh, xa, X8);
  gnn_agg<<<NODES / 16, 256, 0, stream>>>(X8, rowptr, epack, tb);
  gnn_mgru<1><<<NODES / 32, 256, 0, stream>>>(tb, xa, pkRZ[1], pkAI[1], pkAH[1], c1_bi, c1_bh, xc, X8);

  // ---- conv2 ----
  gnn_agg<<<NODES / 16, 256, 0, stream>>>(X8, rowptr, epack, tb);
  gnn_mgru<0><<<NODES / 32, 256, 0, stream>>>(tb, xc, pkRZ[2], pkAI[2], pkAH[2], c2_bi, c2_bh, xa, X8);
  gnn_agg<<<NODES / 16, 256, 0, stream>>>(X8, rowptr, epack, tb);
  gnn_mgru<1><<<NODES / 32, 256, 0, stream>>>(tb, xa, pkRZ[3], pkAI[3], pkAH[3], c2_bi, c2_bh, xc, nullptr);

  // ---- head GEMMs fused (pool epilogue): xc -> tb, ge ----
  gnn_g1g2<<<NODES / 64, 256, 0, stream>>>(xc, pg1, b_g1, pg2, b_g2, tb, ge);

  // ---- per-graph bias ----
  gnn_gbias<<<NB, 256, 0, stream>>>(ge, W_l1 + 128 * 256, b_l1, gb);

  // ---- MLP fused l1+l2+bound: tb -> out ----
  gnn_l1l2<<<NODES / 64, 256, 0, stream>>>(tb, pl1, gb, pl2, b_l2, W_l3, b_l3, vvs, out);
}